// Round 7
// baseline (77.083 us; speedup 1.0000x reference)
//
#include <hip/hip_runtime.h>

typedef __bf16 bf16;
typedef __attribute__((ext_vector_type(8))) __bf16 bf16x8;
typedef __attribute__((ext_vector_type(4))) __bf16 bf16x4;
typedef __attribute__((ext_vector_type(2))) __bf16 bf16x2;
typedef __attribute__((ext_vector_type(4))) float  f32x4;

#define MFMA16(A,B,C) __builtin_amdgcn_mfma_f32_16x16x32_bf16(A,B,C,0,0,0)

// problem constants
constexpr int ROWS = 262144;
constexpr int DIN  = 38;   // real K of layer 1 (padded to 64)
constexpr int H1N  = 256;
constexpr int H2N  = 256;
constexpr int PN   = 128;
constexpr int WROWS = 64;  // rows per wave (4 mtiles) — 2x arithmetic intensity vs R6
constexpr int CHK  = 80;   // chunk row stride bytes (64B data + 16 pad; bank-uniform)

// ws layout (bytes)
constexpr int W1P_OFF = 0;        // 16nt*2ks*64lanes*16B = 32768
constexpr int W2P_OFF = 32768;    // 16*8*64*16 = 131072
constexpr int VP_OFF  = 163840;   // 8*64*16 = 8192
constexpr int C_OFF   = 172032;   // 6 floats

// ---------------------------------------------------------------------------
// Prep (blockIdx-branched, wave-uniform) — unchanged (fast)
// ---------------------------------------------------------------------------
__global__ void prep_kernel(const float* __restrict__ W1,
                            const float* __restrict__ W2,
                            const float* __restrict__ W3,
                            const float* __restrict__ b3,
                            const float* __restrict__ lw_i, const float* __restrict__ bew_i,
                            const float* __restrict__ lw_e, const float* __restrict__ bew_e,
                            const float* __restrict__ lw_m, const float* __restrict__ bew_m,
                            unsigned char* __restrict__ ws)
{
    const int b   = blockIdx.x;
    const int tid = threadIdx.x;

    if (b < 8) {                         // ---- W1 pack ----
        const int u = b * 256 + tid;
        const int lane = u & 63, ks = (u >> 6) & 1, nt = u >> 7;
        const int n  = nt * 16 + (lane & 15);
        const int kb = ks * 32 + (lane >> 4) * 8;
        bf16x8 v;
        #pragma unroll
        for (int i = 0; i < 8; ++i) {
            const int k = kb + i;
            v[i] = (bf16)(k < DIN ? W1[n * DIN + k] : 0.f);
        }
        ((bf16x8*)(ws + W1P_OFF))[u] = v;
    } else if (b < 40) {                 // ---- W2 pack ----
        const int u = (b - 8) * 256 + tid;
        const int lane = u & 63, ks = (u >> 6) & 7, nt = u >> 9;
        const int n  = nt * 16 + (lane & 15);
        const int kb = ks * 32 + (lane >> 4) * 8;
        const float4 v0 = *(const float4*)(W2 + n * H1N + kb);
        const float4 v1 = *(const float4*)(W2 + n * H1N + kb + 4);
        bf16x8 v;
        v[0] = (bf16)v0.x; v[1] = (bf16)v0.y; v[2] = (bf16)v0.z; v[3] = (bf16)v0.w;
        v[4] = (bf16)v1.x; v[5] = (bf16)v1.y; v[6] = (bf16)v1.z; v[7] = (bf16)v1.w;
        ((bf16x8*)(ws + W2P_OFF))[u] = v;
    } else if (b == 40) {                // ---- V fold ----
        __shared__ float wv[6][PN];
        const float* __restrict__ srcs[6] = {lw_i, bew_i, lw_e, bew_e, lw_m, bew_m};
        if (tid < PN) {
            #pragma unroll
            for (int h = 0; h < 6; ++h) wv[h][tid] = srcs[h][tid];
        }
        __syncthreads();
        const int k = tid;
        float s[6] = {0.f, 0.f, 0.f, 0.f, 0.f, 0.f};
        #pragma unroll 4
        for (int p = 0; p < PN; ++p) {
            const float w3 = W3[p * H2N + k];
            #pragma unroll
            for (int h = 0; h < 6; ++h) s[h] += wv[h][p] * w3;
        }
        const int ks = k >> 5, lq = (k >> 3) & 3, i = k & 7;
        unsigned char* vp = ws + VP_OFF;
        #pragma unroll
        for (int h = 0; h < 6; ++h)
            *(bf16*)(vp + (ks * 64 + lq * 16 + h) * 16 + i * 2) = (bf16)s[h];
        #pragma unroll
        for (int h = 6; h < 16; ++h)
            *(bf16*)(vp + (ks * 64 + lq * 16 + h) * 16 + i * 2) = (bf16)0.f;
    } else {                             // ---- c scalars ----
        __shared__ float red[6][PN];
        const float* __restrict__ srcs[6] = {lw_i, bew_i, lw_e, bew_e, lw_m, bew_m};
        if (tid < PN) {
            const float bv = b3[tid];
            #pragma unroll
            for (int h = 0; h < 6; ++h) red[h][tid] = bv * srcs[h][tid];
        }
        __syncthreads();
        if (tid < 6) {
            float s = 0.f;
            for (int p = 0; p < PN; ++p) s += red[tid][p];
            ((float*)(ws + C_OFF))[tid] = s;
        }
    }
}

// ---------------------------------------------------------------------------
// Wave-local fused MLP, 64 rows/wave (4 mtiles), ZERO barriers.
// Weight traffic: 168 KB per 64 rows (half of R6). h1 fragments built
// incrementally through a 5 KB chunked transpose buffer: per 32-neuron group,
// write 2 C-tiles -> read fragments back (same-wave DS ordering). h1 frags
// live in 128 VGPRs for the whole L2 phase; head MFMAs fused into L2 loop.
// Chunk stride 80 B: b64 writes and b128 reads land bank-uniform (min clocks).
// ---------------------------------------------------------------------------
__global__ __launch_bounds__(256, 2)
void fused_kernel(const float* __restrict__ X,
                  const float* __restrict__ b1,
                  const float* __restrict__ b2,
                  const unsigned char* __restrict__ ws,
                  const float* __restrict__ lb_i, const float* __restrict__ beb_i,
                  const float* __restrict__ bw_i, const float* __restrict__ bb_i,
                  const float* __restrict__ lb_e, const float* __restrict__ beb_e,
                  const float* __restrict__ bw_e, const float* __restrict__ bb_e,
                  const float* __restrict__ lb_m, const float* __restrict__ beb_m,
                  const float* __restrict__ bw_m, const float* __restrict__ bb_m,
                  float* __restrict__ out)
{
    __shared__ __attribute__((aligned(16))) unsigned char sC[4][WROWS * CHK]; // 20 KB

    const int tid  = threadIdx.x;
    const int lane = tid & 63;
    const int wid  = tid >> 6;
    const int lr   = lane & 15;
    const int lq   = lane >> 4;
    unsigned char* const myC = sC[wid];
    const int rowbase = blockIdx.x * (4 * WROWS) + wid * WROWS;

    const bf16x8* __restrict__ W1p = (const bf16x8*)(ws + W1P_OFF);
    const bf16x8* __restrict__ W2p = (const bf16x8*)(ws + W2P_OFF);
    const bf16x8* __restrict__ Vp  = (const bf16x8*)(ws + VP_OFF);
    const float*  __restrict__ cvec = (const float*)(ws + C_OFF);

    // ---- X fragments direct from global (no LDS, no barrier) ----
    bf16x8 xf[4][2];   // [mt][ks]
    #pragma unroll
    for (int mt = 0; mt < 4; ++mt) {
        const float* xr = X + (size_t)(rowbase + mt * 16 + lr) * DIN;
        const float2 a0 = *(const float2*)(xr + lq * 8 + 0);
        const float2 a1 = *(const float2*)(xr + lq * 8 + 2);
        const float2 a2 = *(const float2*)(xr + lq * 8 + 4);
        const float2 a3 = *(const float2*)(xr + lq * 8 + 6);
        bf16x8 v0;
        v0[0] = (bf16)a0.x; v0[1] = (bf16)a0.y; v0[2] = (bf16)a1.x; v0[3] = (bf16)a1.y;
        v0[4] = (bf16)a2.x; v0[5] = (bf16)a2.y; v0[6] = (bf16)a3.x; v0[7] = (bf16)a3.y;
        xf[mt][0] = v0;
        bf16x8 v1;
        #pragma unroll
        for (int i = 0; i < 8; ++i) v1[i] = (bf16)0.f;
        if (lq == 0) {
            const float2 c0 = *(const float2*)(xr + 32);
            const float2 c1 = *(const float2*)(xr + 34);
            const float2 c2 = *(const float2*)(xr + 36);
            v1[0] = (bf16)c0.x; v1[1] = (bf16)c0.y; v1[2] = (bf16)c1.x;
            v1[3] = (bf16)c1.y; v1[4] = (bf16)c2.x; v1[5] = (bf16)c2.y;
        }
        xf[mt][1] = v1;
    }

    // ---- layer 1: per 32-neuron group -> chunk -> h1 fragments (VGPR) ----
    bf16x8 hf[4][8];   // [mt][ks] — resident through L2 phase (128 VGPR)
    #pragma unroll
    for (int ko = 0; ko < 8; ++ko) {
        #pragma unroll
        for (int jl = 0; jl < 2; ++jl) {
            const int j = ko * 2 + jl;
            const bf16x8 w0 = W1p[(j * 2 + 0) * 64 + lane];
            const bf16x8 w1 = W1p[(j * 2 + 1) * 64 + lane];
            f32x4 a[4];
            #pragma unroll
            for (int mt = 0; mt < 4; ++mt) {
                a[mt] = (f32x4){0.f, 0.f, 0.f, 0.f};
                a[mt] = MFMA16(w0, xf[mt][0], a[mt]);
                a[mt] = MFMA16(w1, xf[mt][1], a[mt]);
            }
            const float4 bias = *(const float4*)(b1 + j * 16 + lq * 4);
            const float ba[4] = {bias.x, bias.y, bias.z, bias.w};
            #pragma unroll
            for (int mt = 0; mt < 4; ++mt) {
                bf16x4 hv;
                #pragma unroll
                for (int r2 = 0; r2 < 4; ++r2)
                    hv[r2] = (bf16)fmaxf(a[mt][r2] + ba[r2], 0.f);
                *(bf16x4*)(myC + (mt * 16 + lr) * CHK + jl * 32 + lq * 8) = hv;
            }
        }
        #pragma unroll
        for (int mt = 0; mt < 4; ++mt)
            hf[mt][ko] = *(const bf16x8*)(myC + (mt * 16 + lr) * CHK + lq * 16);
    }

    // ---- layer 2 + fused head: per 32-neuron group ----
    f32x4 accH[4];
    #pragma unroll
    for (int mt = 0; mt < 4; ++mt) accH[mt] = (f32x4){0.f, 0.f, 0.f, 0.f};

    for (int jp = 0; jp < 8; ++jp) {
        #pragma unroll
        for (int jl = 0; jl < 2; ++jl) {
            const int j = jp * 2 + jl;
            f32x4 a[4];
            #pragma unroll
            for (int mt = 0; mt < 4; ++mt) a[mt] = (f32x4){0.f, 0.f, 0.f, 0.f};
            #pragma unroll
            for (int ks = 0; ks < 8; ++ks) {
                const bf16x8 w = W2p[(j * 8 + ks) * 64 + lane];
                #pragma unroll
                for (int mt = 0; mt < 4; ++mt)
                    a[mt] = MFMA16(w, hf[mt][ks], a[mt]);
            }
            const float4 bias = *(const float4*)(b2 + j * 16 + lq * 4);
            const float ba[4] = {bias.x, bias.y, bias.z, bias.w};
            #pragma unroll
            for (int mt = 0; mt < 4; ++mt) {
                bf16x4 hv;
                #pragma unroll
                for (int r2 = 0; r2 < 4; ++r2)
                    hv[r2] = (bf16)fmaxf(a[mt][r2] + ba[r2], 0.f);
                *(bf16x4*)(myC + (mt * 16 + lr) * CHK + jl * 32 + lq * 8) = hv;
            }
        }
        const bf16x8 vf = Vp[jp * 64 + lane];
        #pragma unroll
        for (int mt = 0; mt < 4; ++mt) {
            const bf16x8 h2f = *(const bf16x8*)(myC + (mt * 16 + lr) * CHK + lq * 16);
            accH[mt] = MFMA16(vf, h2f, accH[mt]);
        }
    }

    // ---- epilogue: X scalars (tail-loaded; rows are L2-warm) + heads ----
    float ep0[4], ep7[4], ep9[4], ep12[4];
    if (lq == 0) {
        #pragma unroll
        for (int mt = 0; mt < 4; ++mt) {
            const float* xr = X + (size_t)(rowbase + mt * 16 + lr) * DIN;
            ep0[mt] = xr[0]; ep7[mt] = xr[7]; ep9[mt] = xr[9]; ep12[mt] = xr[12];
        }
    }
    const float hlb[3]  = {lb_i[0],  lb_e[0],  lb_m[0]};
    const float hbeb[3] = {beb_i[0], beb_e[0], beb_m[0]};
    const float hbw[3]  = {bw_i[0],  bw_e[0],  bw_m[0]};
    const float hbb[3]  = {bb_i[0],  bb_e[0],  bb_m[0]};
    #pragma unroll
    for (int mt = 0; mt < 4; ++mt) {
        const float d4 = __shfl(accH[mt][0], lane + 16);
        const float d5 = __shfl(accH[mt][1], lane + 16);
        if (lq == 0) {
            const float dots[6] = {accH[mt][0], accH[mt][1], accH[mt][2], accH[mt][3], d4, d5};
            const float xres[3] = {ep7[mt], ep9[mt], ep12[mt]};
            const int row = rowbase + mt * 16 + lr;
            #pragma unroll
            for (int h = 0; h < 3; ++h) {
                const float lin = dots[2 * h] + cvec[2 * h] + hlb[h];
                const float e   = (dots[2 * h + 1] + cvec[2 * h + 1]) * ep0[mt] + hbeb[h];
                const float y   = hbw[h] * e * lin + hbb[h] + xres[h];
                out[(size_t)row * 3 + h] = y;
            }
        }
    }
}

extern "C" void kernel_launch(void* const* d_in, const int* in_sizes, int n_in,
                              void* d_out, int out_size, void* d_ws, size_t ws_size,
                              hipStream_t stream) {
    const float* X   = (const float*)d_in[0];
    const float* W1  = (const float*)d_in[1];
    const float* b1  = (const float*)d_in[2];
    const float* W2  = (const float*)d_in[3];
    const float* b2  = (const float*)d_in[4];
    const float* W3  = (const float*)d_in[5];
    const float* b3  = (const float*)d_in[6];
    const float* lw_i  = (const float*)d_in[7];
    const float* lb_i  = (const float*)d_in[8];
    const float* bew_i = (const float*)d_in[9];
    const float* beb_i = (const float*)d_in[10];
    const float* bw_i  = (const float*)d_in[11];
    const float* bb_i  = (const float*)d_in[12];
    const float* lw_e  = (const float*)d_in[13];
    const float* lb_e  = (const float*)d_in[14];
    const float* bew_e = (const float*)d_in[15];
    const float* beb_e = (const float*)d_in[16];
    const float* bw_e  = (const float*)d_in[17];
    const float* bb_e  = (const float*)d_in[18];
    const float* lw_m  = (const float*)d_in[19];
    const float* lb_m  = (const float*)d_in[20];
    const float* bew_m = (const float*)d_in[21];
    const float* beb_m = (const float*)d_in[22];
    const float* bw_m  = (const float*)d_in[23];
    const float* bb_m  = (const float*)d_in[24];

    unsigned char* ws = (unsigned char*)d_ws;
    float* outp = (float*)d_out;

    prep_kernel<<<42, 256, 0, stream>>>(W1, W2, W3, b3,
                                        lw_i, bew_i, lw_e, bew_e, lw_m, bew_m, ws);

    // 4096 waves, 4 per block, each wave fully independent (64 rows, no barriers)
    fused_kernel<<<ROWS / (4 * WROWS), 256, 0, stream>>>(X, b1, b2, ws,
                                                         lb_i, beb_i, bw_i, bb_i,
                                                         lb_e, beb_e, bw_e, bb_e,
                                                         lb_m, beb_m, bw_m, bb_m,
                                                         outp);
}